// Round 11
// baseline (454.419 us; speedup 1.0000x reference)
//
#include <hip/hip_runtime.h>
#include <hip/hip_bf16.h>

#define N_ATOMS 100000
#define N_PAIRS 2000000
#define N_EMB 30
#define N_DIST 100
#define N_HID 60

#define TE 64                       // edges per tile
#define NTILES (N_PAIRS / TE)       // 31250 exact
#define EBLOCKS 512                 // 2 blocks/CU

typedef short bf16x8 __attribute__((ext_vector_type(8)));
typedef float f32x4 __attribute__((ext_vector_type(4)));

__device__ __forceinline__ ushort f2bf(float f) {
    __hip_bfloat16 h = __float2bfloat16(f);
    return __builtin_bit_cast(ushort, h);
}
__device__ __forceinline__ float fast_tanh(float x) {
    float e = __expf(2.0f * x);
    return 1.0f - 2.0f / (e + 1.0f);
}

// raw barrier: LDS-visibility only; leaves global loads in flight (proven r9)
__device__ __forceinline__ void lds_barrier() {
    asm volatile("s_waitcnt lgkmcnt(0)" ::: "memory");
    __builtin_amdgcn_s_barrier();
    __builtin_amdgcn_sched_barrier(0);
}

// ---------------- Kernel A: per-atom hidden + output init ----------------
__global__ __launch_bounds__(256) void atom_kernel(
    const float* __restrict__ af, const float* __restrict__ W_cf,
    const float* __restrict__ W_fc, const float* __restrict__ b_cf,
    const float* __restrict__ b_df, float* __restrict__ ah_out,
    float* __restrict__ out)
{
    __shared__ __align__(16) float ah_lds[4][N_HID];
    const int wave = threadIdx.x >> 6;
    const int lane = threadIdx.x & 63;
    const int n = blockIdx.x * 4 + wave;

    float ahv = 0.f;
    if (lane < N_HID) {
        ahv = b_cf[lane];
        #pragma unroll
        for (int k = 0; k < N_EMB; ++k)
            ahv = fmaf(af[(size_t)n * N_EMB + k], W_cf[k * N_HID + lane], ahv);
        ah_out[(size_t)n * N_HID + lane] = ahv;
        ah_lds[wave][lane] = ahv * b_df[lane];
    }
    __syncthreads();
    if (lane < N_EMB) {
        float s = 0.f;
        #pragma unroll
        for (int h = 0; h < N_HID; ++h)
            s = fmaf(ah_lds[wave][h], W_fc[h * N_EMB + lane], s);
        out[(size_t)n * N_EMB + lane] =
            af[(size_t)n * N_EMB + lane] - fast_tanh(s);
    }
}

// ---------------- Kernel B: cooperative staging + wave-autonomous compute ----------------
// Per tile (64 edges): block stages dist tile coalesced into dbuf A_lds (1 barrier).
// Wave wv owns edges [16wv,16wv+16): reads A ONCE (4 ds_read_b128), computes all
// 60 hid via wdf VGPR frags, T bounce in wave-private LDS, MFMA2, per-wave scan.
__global__ __launch_bounds__(256, 2) void edge_kernel(
    const float* __restrict__ dist,
    const int* __restrict__ mi, const int* __restrict__ mj,
    const float* __restrict__ W_df, const float* __restrict__ W_fc,
    const float* __restrict__ b_df, const float* __restrict__ ah,
    float* out)
{
    __shared__ ushort A_lds[2][TE * 136];     // 34816 B (dbuf dist tile, bf16)
    __shared__ ushort T_all[4][16 * 72];      // 9216 B (wave-private T)
    // total 44032 B -> 2 blocks/CU (with 8 waves/CU)

    const int tid = threadIdx.x;
    const int wv = tid >> 6, lane = tid & 63;
    const int l4 = lane >> 4, ln = lane & 15;
    ushort* Tw = T_all[wv];

    // ---- one-time weight fragments (r6/r10-proven layout) ----
    bf16x8 wdf[4][4];                         // [ks][hg]: k=ks*32+l4*8+i, h=hg*16+ln
    #pragma unroll
    for (int ks = 0; ks < 4; ++ks) {
        #pragma unroll
        for (int hg = 0; hg < 4; ++hg) {
            #pragma unroll
            for (int i = 0; i < 8; ++i) {
                int k = ks * 32 + l4 * 8 + i, h = hg * 16 + ln;
                float f = (k < N_DIST && h < N_HID) ? W_df[k * N_HID + h] : 0.f;
                wdf[ks][hg][i] = (short)f2bf(f);
            }
        }
    }
    bf16x8 wfc[2][2];                         // [nf][ks]: k=ks*32+l4*8+i, col=nf*16+ln
    #pragma unroll
    for (int nf = 0; nf < 2; ++nf) {
        #pragma unroll
        for (int ks = 0; ks < 2; ++ks) {
            #pragma unroll
            for (int i = 0; i < 8; ++i) {
                int k = ks * 32 + l4 * 8 + i, n = nf * 16 + ln;
                float f = (k < N_HID && n < N_EMB) ? W_fc[k * N_EMB + n] : 0.f;
                wfc[nf][ks][i] = (short)f2bf(f);
            }
        }
    }
    float bdf[4];
    #pragma unroll
    for (int hg = 0; hg < 4; ++hg) {
        int h = hg * 16 + ln;
        bdf[hg] = (h < N_HID) ? b_df[h] : 0.f;
    }

    // zero A pad columns [100..136) in both buffers (never rewritten)
    for (int idx = tid; idx < 2 * TE * 36; idx += 256) {
        int b = idx / (TE * 36), rem = idx % (TE * 36);
        int r = rem / 36, c = 100 + rem % 36;
        A_lds[b][r * 136 + c] = 0;
    }

    const int t0 = (int)(((long long)blockIdx.x * NTILES) / EBLOCKS);
    const int t1 = (int)(((long long)(blockIdx.x + 1) * NTILES) / EBLOCKS);

    // ---- coalesced staging (r8-proven lambdas, minus metadata) ----
    f32x4 pf[7];
    auto issue_pf = [&](int t) {
        const f32x4* src = (const f32x4*)(dist + (size_t)t * TE * N_DIST);
        #pragma unroll
        for (int k = 0; k < 6; ++k)
            pf[k] = __builtin_nontemporal_load(&src[k * 256 + tid]);
        if (tid < 64) pf[6] = __builtin_nontemporal_load(&src[6 * 256 + tid]);
    };
    auto write_pf = [&](int buf) {
        #pragma unroll
        for (int k = 0; k < 7; ++k) {
            int idx = k * 256 + tid;
            if (k < 6 || tid < 64) {
                int r = idx / 25, c = idx % 25;
                f32x4 v = pf[k];
                ushort4 pk2;
                pk2.x = f2bf(v[0]); pk2.y = f2bf(v[1]);
                pk2.z = f2bf(v[2]); pk2.w = f2bf(v[3]);
                *(ushort4*)&A_lds[buf][r * 136 + c * 4] = pk2;
            }
        }
    };

    // prologue: stage tile t0 into buffer 0
    issue_pf(t0);
    write_pf(0);
    lds_barrier();

    int cur = 0;
    for (int t = t0; t < t1; ++t) {
        const bool hasnext = (t + 1 < t1);
        const int eb = t * TE + wv * 16;      // this wave's 16 edges

        // ---- per-wave edge metadata (lane ln holds edge eb+ln, dup over l4) ----
        const int miv = mi[eb + ln];
        const int mjv = mj[eb + ln];

        // ---- gather ah FIRST (so its waitcnt leaves the dist prefetch in flight) ----
        int jr[4];
        #pragma unroll
        for (int r = 0; r < 4; ++r) jr[r] = __shfl(mjv, l4 * 4 + r);
        float ahg[4][4];
        #pragma unroll
        for (int hg = 0; hg < 4; ++hg) {
            int h = hg * 16 + ln;
            #pragma unroll
            for (int r = 0; r < 4; ++r)
                ahg[hg][r] = (h < N_HID) ? ah[(size_t)jr[r] * N_HID + h] : 0.f;
        }

        // ---- issue next tile's dist loads (consumed at write_pf below) ----
        if (hasnext) issue_pf(t + 1);

        // ---- MFMA1: this wave's 16 edges x all 60 hid (A read ONCE) ----
        f32x4 acc1[4] = {{0,0,0,0},{0,0,0,0},{0,0,0,0},{0,0,0,0}};
        #pragma unroll
        for (int ks = 0; ks < 4; ++ks) {
            bf16x8 a = *(const bf16x8*)&A_lds[cur][(wv * 16 + ln) * 136 + ks * 32 + l4 * 8];
            #pragma unroll
            for (int hg = 0; hg < 4; ++hg)
                acc1[hg] = __builtin_amdgcn_mfma_f32_16x16x32_bf16(a, wdf[ks][hg], acc1[hg], 0, 0, 0);
        }

        // ---- T = (dh + b_df) * ah -> bf16 -> wave-private transpose bounce ----
        #pragma unroll
        for (int hg = 0; hg < 4; ++hg) {
            #pragma unroll
            for (int r = 0; r < 4; ++r) {
                float tv = (acc1[hg][r] + bdf[hg]) * ahg[hg][r];
                Tw[(l4 * 4 + r) * 72 + hg * 16 + ln] = f2bf(tv);
            }
        }
        // same-wave RAW: compiler inserts lgkmcnt before these reads
        bf16x8 tA = *(const bf16x8*)&Tw[ln * 72 + l4 * 8];
        bf16x8 tB = *(const bf16x8*)&Tw[ln * 72 + 32 + l4 * 8];

        // ---- MFMA2: 16 edges x 30 f ----
        f32x4 acc2[2] = {{0,0,0,0},{0,0,0,0}};
        #pragma unroll
        for (int nf = 0; nf < 2; ++nf) {
            acc2[nf] = __builtin_amdgcn_mfma_f32_16x16x32_bf16(tA, wfc[nf][0], acc2[nf], 0, 0, 0);
            acc2[nf] = __builtin_amdgcn_mfma_f32_16x16x32_bf16(tB, wfc[nf][1], acc2[nf], 0, 0, 0);
        }

        // ---- tanh + per-lane segment scan over this lane's 4 edges ----
        float s0v[4], s1v[4];
        #pragma unroll
        for (int r = 0; r < 4; ++r) {
            s0v[r] = fast_tanh(acc2[0][r]);
            s1v[r] = fast_tanh(acc2[1][r]);
        }
        int m_r[4];
        #pragma unroll
        for (int r = 0; r < 4; ++r) m_r[r] = __shfl(miv, l4 * 4 + r);

        int cura = m_r[0];
        float f0 = s0v[0], f1 = s1v[0];
        #pragma unroll
        for (int r = 1; r < 4; ++r) {
            if (m_r[r] != cura) {
                atomicAdd(&out[(size_t)cura * N_EMB + ln], f0);
                if (ln < N_EMB - 16) atomicAdd(&out[(size_t)cura * N_EMB + 16 + ln], f1);
                cura = m_r[r]; f0 = s0v[r]; f1 = s1v[r];
            } else {
                f0 += s0v[r]; f1 += s1v[r];
            }
        }
        atomicAdd(&out[(size_t)cura * N_EMB + ln], f0);
        if (ln < N_EMB - 16) atomicAdd(&out[(size_t)cura * N_EMB + 16 + ln], f1);

        // ---- stage next tile into the other buffer; one barrier per tile ----
        if (hasnext) write_pf(cur ^ 1);
        lds_barrier();
        cur ^= 1;
    }
}

extern "C" void kernel_launch(void* const* d_in, const int* in_sizes, int n_in,
                              void* d_out, int out_size, void* d_ws, size_t ws_size,
                              hipStream_t stream) {
    const float* af   = (const float*)d_in[0];
    const float* dist = (const float*)d_in[1];
    const int*   mi   = (const int*)d_in[2];
    const int*   mj   = (const int*)d_in[3];
    const float* W_cf = (const float*)d_in[4];
    const float* W_df = (const float*)d_in[5];
    const float* W_fc = (const float*)d_in[6];
    const float* b_cf = (const float*)d_in[7];
    const float* b_df = (const float*)d_in[8];
    float* out = (float*)d_out;
    float* ah  = (float*)d_ws;   // N_ATOMS * N_HID floats = 24 MB

    atom_kernel<<<N_ATOMS / 4, 256, 0, stream>>>(af, W_cf, W_fc, b_cf, b_df, ah, out);
    edge_kernel<<<EBLOCKS, 256, 0, stream>>>(dist, mi, mj, W_df, W_fc, b_df, ah, out);
}

// Round 12
// 451.666 us; speedup vs baseline: 1.0061x; 1.0061x over previous
//
#include <hip/hip_runtime.h>
#include <hip/hip_bf16.h>

#define N_ATOMS 100000
#define N_PAIRS 2000000
#define N_EMB 30
#define N_DIST 100
#define N_HID 60

#define TE 64                       // edges per tile
#define NTILES (N_PAIRS / TE)       // 31250 exact
#define EBLOCKS 768                 // 3 blocks/CU resident

typedef short bf16x8 __attribute__((ext_vector_type(8)));
typedef float f32x4 __attribute__((ext_vector_type(4)));

__device__ __forceinline__ ushort f2bf(float f) {
    __hip_bfloat16 h = __float2bfloat16(f);
    return __builtin_bit_cast(ushort, h);
}
__device__ __forceinline__ float fast_tanh(float x) {
    float e = __expf(2.0f * x);
    return 1.0f - 2.0f / (e + 1.0f);
}

// ---------------- Kernel A: per-atom hidden + output init ----------------
__global__ __launch_bounds__(256) void atom_kernel(
    const float* __restrict__ af, const float* __restrict__ W_cf,
    const float* __restrict__ W_fc, const float* __restrict__ b_cf,
    const float* __restrict__ b_df, float* __restrict__ ah_out,
    float* __restrict__ out)
{
    __shared__ __align__(16) float ah_lds[4][N_HID];
    const int wave = threadIdx.x >> 6;
    const int lane = threadIdx.x & 63;
    const int n = blockIdx.x * 4 + wave;

    float ahv = 0.f;
    if (lane < N_HID) {
        ahv = b_cf[lane];
        #pragma unroll
        for (int k = 0; k < N_EMB; ++k)
            ahv = fmaf(af[(size_t)n * N_EMB + k], W_cf[k * N_HID + lane], ahv);
        ah_out[(size_t)n * N_HID + lane] = ahv;
        ah_lds[wave][lane] = ahv * b_df[lane];
    }
    __syncthreads();
    if (lane < N_EMB) {
        float s = 0.f;
        #pragma unroll
        for (int h = 0; h < N_HID; ++h)
            s = fmaf(ah_lds[wave][h], W_fc[h * N_EMB + lane], s);
        out[(size_t)n * N_EMB + lane] =
            af[(size_t)n * N_EMB + lane] - fast_tanh(s);
    }
}

// ---------------- Kernel B: r8 dbuf skeleton, selector path deleted ----------------
// Per tile: stage dist (dbuf), MFMA1 (64e x 16hid/wave), T bounce, B2,
// MFMA2 (16e x 32f/wave), tanh + per-lane register scan + atomics, B3.
__global__ __launch_bounds__(256, 3) void edge_kernel(
    const float* __restrict__ dist,
    const int* __restrict__ mi, const int* __restrict__ mj,
    const float* __restrict__ W_df, const float* __restrict__ W_fc,
    const float* __restrict__ b_df, const float* __restrict__ ah,
    float* out)
{
    __shared__ ushort A_lds[2][TE * 136];     // 34816 B (dbuf dist tile, bf16)
    __shared__ ushort T_lds[TE * 72];         // 9216 B
    __shared__ int    mis[2][TE], mjs[2][TE]; // 1024 B
    // total ~45 KB -> 3 blocks/CU

    const int tid = threadIdx.x;
    const int wv = tid >> 6, lane = tid & 63;
    const int l4 = lane >> 4, ln = lane & 15;
    const int h1 = wv * 16 + ln;              // stage-1 hid col for this lane

    // ---- one-time weight fragments (single bf16, r9/r10-proven numerics) ----
    bf16x8 wdf[4];                            // [ks]: k = ks*32 + l4*8 + i, n = h1
    #pragma unroll
    for (int ks = 0; ks < 4; ++ks) {
        #pragma unroll
        for (int i = 0; i < 8; ++i) {
            int k = ks * 32 + l4 * 8 + i;
            float f = (k < N_DIST && h1 < N_HID) ? W_df[k * N_HID + h1] : 0.f;
            wdf[ks][i] = (short)f2bf(f);
        }
    }
    bf16x8 wfc[2][2];                         // [nf][ks]
    #pragma unroll
    for (int nf = 0; nf < 2; ++nf) {
        #pragma unroll
        for (int ks = 0; ks < 2; ++ks) {
            #pragma unroll
            for (int i = 0; i < 8; ++i) {
                int k = ks * 32 + l4 * 8 + i;
                int n = nf * 16 + ln;
                float f = (k < N_HID && n < N_EMB) ? W_fc[k * N_EMB + n] : 0.f;
                wfc[nf][ks][i] = (short)f2bf(f);
            }
        }
    }
    const float bdf1 = (h1 < N_HID) ? b_df[h1] : 0.f;

    // zero A pad columns [100..136) in both buffers (never rewritten)
    for (int idx = tid; idx < 2 * TE * 36; idx += 256) {
        int b = idx / (TE * 36), rem = idx % (TE * 36);
        int r = rem / 36, c = 100 + rem % 36;
        A_lds[b][r * 136 + c] = 0;
    }

    const int t0 = (int)(((long long)blockIdx.x * NTILES) / EBLOCKS);
    const int t1 = (int)(((long long)(blockIdx.x + 1) * NTILES) / EBLOCKS);

    f32x4 pf[7];
    int pmi = 0, pmj = 0;

    auto stage_issue = [&](int t) {
        const f32x4* src = (const f32x4*)(dist + (size_t)t * TE * N_DIST);
        #pragma unroll
        for (int k = 0; k < 6; ++k)
            pf[k] = __builtin_nontemporal_load(&src[k * 256 + tid]);
        if (tid < 64) {
            pf[6] = __builtin_nontemporal_load(&src[6 * 256 + tid]);
            pmi = mi[t * TE + tid];
            pmj = mj[t * TE + tid];
        }
    };
    auto stage_write = [&](int buf) {
        #pragma unroll
        for (int k = 0; k < 7; ++k) {
            int idx = k * 256 + tid;
            if (k < 6 || tid < 64) {
                int r = idx / 25, c = idx % 25;
                f32x4 v = pf[k];
                ushort4 pk2;
                pk2.x = f2bf(v[0]); pk2.y = f2bf(v[1]);
                pk2.z = f2bf(v[2]); pk2.w = f2bf(v[3]);
                *(ushort4*)&A_lds[buf][r * 136 + c * 4] = pk2;
            }
        }
        if (tid < 64) { mis[buf][tid] = pmi; mjs[buf][tid] = pmj; }
    };

    // prologue: stage tile t0 into buffer 0
    stage_issue(t0);
    stage_write(0);
    __syncthreads();

    int cur = 0;
    for (int t = t0; t < t1; ++t) {
        const bool hasnext = (t + 1 < t1);

        // ---- gather first (waitcnt ordering: leaves dist prefetch in flight) ----
        float ahg[4][4];
        #pragma unroll
        for (int m = 0; m < 4; ++m) {
            #pragma unroll
            for (int r = 0; r < 4; ++r) {
                int el = 16 * m + l4 * 4 + r;
                int j = mjs[cur][el];
                ahg[m][r] = (h1 < N_HID) ? ah[(size_t)j * N_HID + h1] : 0.f;
            }
        }

        if (hasnext) stage_issue(t + 1);

        // ---- stage-1 MFMA: 64 edges x 16 hids ----
        f32x4 acc1[4] = {{0,0,0,0},{0,0,0,0},{0,0,0,0},{0,0,0,0}};
        #pragma unroll
        for (int ks = 0; ks < 4; ++ks) {
            #pragma unroll
            for (int m = 0; m < 4; ++m) {
                bf16x8 a = *(const bf16x8*)&A_lds[cur][(16 * m + ln) * 136 + ks * 32 + l4 * 8];
                acc1[m] = __builtin_amdgcn_mfma_f32_16x16x32_bf16(a, wdf[ks], acc1[m], 0, 0, 0);
            }
        }

        // ---- t = (dh + b_df) * ah -> bf16 -> T_lds ----
        #pragma unroll
        for (int m = 0; m < 4; ++m) {
            #pragma unroll
            for (int r = 0; r < 4; ++r) {
                int row = 16 * m + l4 * 4 + r;
                float tv = (acc1[m][r] + bdf1) * ahg[m][r];
                T_lds[row * 72 + h1] = (h1 < N_HID) ? f2bf(tv) : (ushort)0;
            }
        }
        __syncthreads();   // B2: T ready (cross-wave: each T row mixes all waves' hids)

        // ---- stage-2 MFMA: this wave's 16 edges x 32 f ----
        f32x4 acc2[2] = {{0,0,0,0},{0,0,0,0}};
        #pragma unroll
        for (int ks = 0; ks < 2; ++ks) {
            bf16x8 a2 = *(const bf16x8*)&T_lds[(16 * wv + ln) * 72 + ks * 32 + l4 * 8];
            #pragma unroll
            for (int nf = 0; nf < 2; ++nf)
                acc2[nf] = __builtin_amdgcn_mfma_f32_16x16x32_bf16(a2, wfc[nf][ks], acc2[nf], 0, 0, 0);
        }

        // ---- tanh + per-lane register scan over this lane's 4 edges (r10/r11-proven) ----
        // lane(l4,ln): edge e = 16*wv + l4*4 + r ; f = nf*16 + ln
        float s0v[4], s1v[4];
        #pragma unroll
        for (int r = 0; r < 4; ++r) {
            s0v[r] = fast_tanh(acc2[0][r]);
            s1v[r] = fast_tanh(acc2[1][r]);
        }
        {
            int miv = mis[cur][16 * wv + ln];     // lane ln holds edge 16wv+ln's atom
            int m_r[4];
            #pragma unroll
            for (int r = 0; r < 4; ++r) m_r[r] = __shfl(miv, l4 * 4 + r);

            int cura = m_r[0];
            float f0 = s0v[0], f1 = s1v[0];
            #pragma unroll
            for (int r = 1; r < 4; ++r) {
                if (m_r[r] != cura) {
                    atomicAdd(&out[(size_t)cura * N_EMB + ln], f0);
                    if (ln < N_EMB - 16) atomicAdd(&out[(size_t)cura * N_EMB + 16 + ln], f1);
                    cura = m_r[r]; f0 = s0v[r]; f1 = s1v[r];
                } else {
                    f0 += s0v[r]; f1 += s1v[r];
                }
            }
            atomicAdd(&out[(size_t)cura * N_EMB + ln], f0);
            if (ln < N_EMB - 16) atomicAdd(&out[(size_t)cura * N_EMB + 16 + ln], f1);
        }

        // write next tile's A while atomics drain
        if (hasnext) stage_write(cur ^ 1);

        __syncthreads();   // B3: next A/metadata ready; T free for overwrite
        cur ^= 1;
    }
}

extern "C" void kernel_launch(void* const* d_in, const int* in_sizes, int n_in,
                              void* d_out, int out_size, void* d_ws, size_t ws_size,
                              hipStream_t stream) {
    const float* af   = (const float*)d_in[0];
    const float* dist = (const float*)d_in[1];
    const int*   mi   = (const int*)d_in[2];
    const int*   mj   = (const int*)d_in[3];
    const float* W_cf = (const float*)d_in[4];
    const float* W_df = (const float*)d_in[5];
    const float* W_fc = (const float*)d_in[6];
    const float* b_cf = (const float*)d_in[7];
    const float* b_df = (const float*)d_in[8];
    float* out = (float*)d_out;
    float* ah  = (float*)d_ws;   // N_ATOMS * N_HID floats = 24 MB

    atom_kernel<<<N_ATOMS / 4, 256, 0, stream>>>(af, W_cf, W_fc, b_cf, b_df, ah, out);
    edge_kernel<<<EBLOCKS, 256, 0, stream>>>(dist, mi, mj, W_df, W_fc, b_df, ah, out);
}

// Round 13
// 306.041 us; speedup vs baseline: 1.4848x; 1.4758x over previous
//
#include <hip/hip_runtime.h>
#include <hip/hip_bf16.h>

#define N_ATOMS 100000
#define N_PAIRS 2000000
#define N_EMB 30
#define N_DIST 100
#define N_HID 60

#define TE 64                       // edges per tile
#define NTILES (N_PAIRS / TE)       // 31250 exact
#define EBLOCKS 768                 // 3 blocks/CU resident

typedef short bf16x8 __attribute__((ext_vector_type(8)));
typedef float f32x4 __attribute__((ext_vector_type(4)));

__device__ __forceinline__ ushort f2bf(float f) {
    __hip_bfloat16 h = __float2bfloat16(f);
    return __builtin_bit_cast(ushort, h);
}
__device__ __forceinline__ float fast_tanh(float x) {
    float e = __expf(2.0f * x);
    return 1.0f - 2.0f / (e + 1.0f);
}

// raw barrier: LDS-visibility only (lgkmcnt), leaves global loads in flight
__device__ __forceinline__ void lds_barrier() {
    asm volatile("s_waitcnt lgkmcnt(0)" ::: "memory");
    __builtin_amdgcn_s_barrier();
    __builtin_amdgcn_sched_barrier(0);
}

// ---------------- Kernel A: per-atom hidden + output init ----------------
__global__ __launch_bounds__(256) void atom_kernel(
    const float* __restrict__ af, const float* __restrict__ W_cf,
    const float* __restrict__ W_fc, const float* __restrict__ b_cf,
    const float* __restrict__ b_df, float* __restrict__ ah_out,
    float* __restrict__ out)
{
    __shared__ __align__(16) float ah_lds[4][N_HID];
    const int wave = threadIdx.x >> 6;
    const int lane = threadIdx.x & 63;
    const int n = blockIdx.x * 4 + wave;

    float ahv = 0.f;
    if (lane < N_HID) {
        ahv = b_cf[lane];
        #pragma unroll
        for (int k = 0; k < N_EMB; ++k)
            ahv = fmaf(af[(size_t)n * N_EMB + k], W_cf[k * N_HID + lane], ahv);
        ah_out[(size_t)n * N_HID + lane] = ahv;
        ah_lds[wave][lane] = ahv * b_df[lane];
    }
    __syncthreads();
    if (lane < N_EMB) {
        float s = 0.f;
        #pragma unroll
        for (int h = 0; h < N_HID; ++h)
            s = fmaf(ah_lds[wave][h], W_fc[h * N_EMB + lane], s);
        out[(size_t)n * N_EMB + lane] =
            af[(size_t)n * N_EMB + lane] - fast_tanh(s);
    }
}

// ---------------- Kernel B: dbuf + selector, raw barriers, gather 1 tile ahead ----------------
__global__ __launch_bounds__(256, 3) void edge_kernel(
    const float* __restrict__ dist,
    const int* __restrict__ mi, const int* __restrict__ mj,
    const float* __restrict__ W_df, const float* __restrict__ W_fc,
    const float* __restrict__ b_df, const float* __restrict__ ah,
    float* out)
{
    __shared__ ushort A_lds[2][TE * 136];     // 34816 B (dbuf dist tile, bf16)
    __shared__ ushort T_lds[TE * 72];         // 9216 B
    __shared__ ushort S_lds[32 * 72];         // 4608 B  (S^T: [f][edge])
    __shared__ int    mis[2][TE], mjs[2][TE]; // 1024 B
    __shared__ int    seg_lds[TE];            // 256 B
    __shared__ int    seg_atom[TE];           // 256 B

    const int tid = threadIdx.x;
    const int wv = tid >> 6, lane = tid & 63;
    const int l4 = lane >> 4, ln = lane & 15;
    const int h1 = wv * 16 + ln;              // stage-1 hid col for this lane

    // ---- one-time weight fragments (single bf16; r9-validated numerics) ----
    bf16x8 wdf[4];                            // [ks]: k = ks*32 + l4*8 + i, n = h1
    #pragma unroll
    for (int ks = 0; ks < 4; ++ks) {
        #pragma unroll
        for (int i = 0; i < 8; ++i) {
            int k = ks * 32 + l4 * 8 + i;
            float f = (k < N_DIST && h1 < N_HID) ? W_df[k * N_HID + h1] : 0.f;
            wdf[ks][i] = (short)f2bf(f);
        }
    }
    bf16x8 wfc[2][2];                         // [nf][ks]
    #pragma unroll
    for (int nf = 0; nf < 2; ++nf) {
        #pragma unroll
        for (int ks = 0; ks < 2; ++ks) {
            #pragma unroll
            for (int i = 0; i < 8; ++i) {
                int k = ks * 32 + l4 * 8 + i;
                int n = nf * 16 + ln;
                float f = (k < N_HID && n < N_EMB) ? W_fc[k * N_EMB + n] : 0.f;
                wfc[nf][ks][i] = (short)f2bf(f);
            }
        }
    }
    const float bdf1 = (h1 < N_HID) ? b_df[h1] : 0.f;

    // zero A pad columns [100..136) in both buffers (never rewritten)
    for (int idx = tid; idx < 2 * TE * 36; idx += 256) {
        int b = idx / (TE * 36), rem = idx % (TE * 36);
        int r = rem / 36, c = 100 + rem % 36;
        A_lds[b][r * 136 + c] = 0;
    }

    const int t0 = (int)(((long long)blockIdx.x * NTILES) / EBLOCKS);
    const int t1 = (int)(((long long)(blockIdx.x + 1) * NTILES) / EBLOCKS);

    f32x4 pf[7];
    int pmi = 0, pmj = 0;

    auto stage_issue = [&](int t) {
        const f32x4* src = (const f32x4*)(dist + (size_t)t * TE * N_DIST);
        #pragma unroll
        for (int k = 0; k < 6; ++k)
            pf[k] = __builtin_nontemporal_load(&src[k * 256 + tid]);
        if (tid < 64) {
            pf[6] = __builtin_nontemporal_load(&src[6 * 256 + tid]);
            pmi = mi[t * TE + tid];
            pmj = mj[t * TE + tid];
        }
    };
    auto stage_write = [&](int buf) {
        #pragma unroll
        for (int k = 0; k < 7; ++k) {
            int idx = k * 256 + tid;
            if (k < 6 || tid < 64) {
                int r = idx / 25, c = idx % 25;
                f32x4 v = pf[k];
                ushort4 pk2;
                pk2.x = f2bf(v[0]); pk2.y = f2bf(v[1]);
                pk2.z = f2bf(v[2]); pk2.w = f2bf(v[3]);
                *(ushort4*)&A_lds[buf][r * 136 + c * 4] = pk2;
            }
        }
        if (tid < 64) { mis[buf][tid] = pmi; mjs[buf][tid] = pmj; }
    };

    float ahg[4][4];                           // gather buffer, refilled once per tile
    auto gather = [&](int buf) {
        #pragma unroll
        for (int m = 0; m < 4; ++m) {
            #pragma unroll
            for (int r = 0; r < 4; ++r) {
                int el = 16 * m + l4 * 4 + r;
                int j = mjs[buf][el];
                ahg[m][r] = (h1 < N_HID) ? ah[(size_t)j * N_HID + h1] : 0.f;
            }
        }
    };

    // prologue: stage tile t0, gather its ah rows
    stage_issue(t0);
    stage_write(0);
    __syncthreads();
    gather(0);

    int cur = 0;
    for (int t = t0; t < t1; ++t) {
        const bool hasnext = (t + 1 < t1);

        // issue next tile's dist loads; they stay in flight across raw barriers
        if (hasnext) stage_issue(t + 1);

        // ---- stage-1 MFMA: 64 edges x 16 hids ----
        f32x4 acc1[4] = {{0,0,0,0},{0,0,0,0},{0,0,0,0},{0,0,0,0}};
        #pragma unroll
        for (int ks = 0; ks < 4; ++ks) {
            #pragma unroll
            for (int m = 0; m < 4; ++m) {
                bf16x8 a = *(const bf16x8*)&A_lds[cur][(16 * m + ln) * 136 + ks * 32 + l4 * 8];
                acc1[m] = __builtin_amdgcn_mfma_f32_16x16x32_bf16(a, wdf[ks], acc1[m], 0, 0, 0);
            }
        }

        // ---- t = (dh + b_df) * ah (gathered LAST tile -> fully covered) -> T_lds ----
        #pragma unroll
        for (int m = 0; m < 4; ++m) {
            #pragma unroll
            for (int r = 0; r < 4; ++r) {
                int row = 16 * m + l4 * 4 + r;
                float tv = (acc1[m][r] + bdf1) * ahg[m][r];
                T_lds[row * 72 + h1] = (h1 < N_HID) ? f2bf(tv) : (ushort)0;
            }
        }
        lds_barrier();   // B2: T visible; A[cur] readers done

        // ---- stage-2 MFMA: 16 edges x 32 f ----
        f32x4 acc2[2] = {{0,0,0,0},{0,0,0,0}};
        #pragma unroll
        for (int ks = 0; ks < 2; ++ks) {
            bf16x8 a2 = *(const bf16x8*)&T_lds[(16 * wv + ln) * 72 + ks * 32 + l4 * 8];
            #pragma unroll
            for (int nf = 0; nf < 2; ++nf)
                acc2[nf] = __builtin_amdgcn_mfma_f32_16x16x32_bf16(a2, wfc[nf][ks], acc2[nf], 0, 0, 0);
        }
        // tanh -> S^T (bf16); rows f>=30 exact zeros
        #pragma unroll
        for (int nf = 0; nf < 2; ++nf) {
            #pragma unroll
            for (int r = 0; r < 4; ++r) {
                int f = nf * 16 + ln;
                int e = 16 * wv + l4 * 4 + r;
                S_lds[f * 72 + e] = f2bf(fast_tanh(acc2[nf][r]));
            }
        }

        // write next tile's A + metadata (pf waited via per-thread vmcnt at ds_write)
        if (hasnext) stage_write(cur ^ 1);

        lds_barrier();   // B3: S + next A/metadata visible

        // issue next tile's gather NOW: consumed at next T-multiply (~full-tile cover)
        if (hasnext) gather(cur ^ 1);

        // ---- per-tile segment metadata (redundant per wave, identical) ----
        int m_e = mis[cur][lane];
        int prevv = __shfl_up(m_e, 1);
        bool changed = (lane > 0) && (m_e != prevv);
        unsigned long long bmask = __ballot(changed);
        int segl = __popcll(bmask & ((2ull << lane) - 1ull));
        if (lane == 0 || changed) seg_atom[segl] = m_e;
        seg_lds[lane] = segl;
        int nseg = __popcll(bmask) + 1;

        // ---- selector MFMA: C[seg][f] = sel[seg][e] @ S[e][f] ----
        int myseg = 16 * wv + ln;
        f32x4 acc3[2] = {{0,0,0,0},{0,0,0,0}};
        #pragma unroll
        for (int ks = 0; ks < 2; ++ks) {
            bf16x8 sfr;
            const int* sp = &seg_lds[ks * 32 + l4 * 8];
            #pragma unroll
            for (int i = 0; i < 8; ++i)
                sfr[i] = (sp[i] == myseg) ? (short)0x3F80 : (short)0;
            #pragma unroll
            for (int nf = 0; nf < 2; ++nf) {
                bf16x8 b = *(const bf16x8*)&S_lds[(nf * 16 + ln) * 72 + ks * 32 + l4 * 8];
                acc3[nf] = __builtin_amdgcn_mfma_f32_16x16x32_bf16(sfr, b, acc3[nf], 0, 0, 0);
            }
        }
        // ---- flush: one atomicAdd per (present segment, f), conflict-free ----
        #pragma unroll
        for (int nf = 0; nf < 2; ++nf) {
            #pragma unroll
            for (int r = 0; r < 4; ++r) {
                int gs = 16 * wv + l4 * 4 + r;
                int f = nf * 16 + ln;
                if (gs < nseg && f < N_EMB) {
                    int atomId = seg_atom[gs];
                    atomicAdd(&out[(size_t)atomId * N_EMB + f], acc3[nf][r]);
                }
            }
        }
        cur ^= 1;
    }
}

extern "C" void kernel_launch(void* const* d_in, const int* in_sizes, int n_in,
                              void* d_out, int out_size, void* d_ws, size_t ws_size,
                              hipStream_t stream) {
    const float* af   = (const float*)d_in[0];
    const float* dist = (const float*)d_in[1];
    const int*   mi   = (const int*)d_in[2];
    const int*   mj   = (const int*)d_in[3];
    const float* W_cf = (const float*)d_in[4];
    const float* W_df = (const float*)d_in[5];
    const float* W_fc = (const float*)d_in[6];
    const float* b_cf = (const float*)d_in[7];
    const float* b_df = (const float*)d_in[8];
    float* out = (float*)d_out;
    float* ah  = (float*)d_ws;   // N_ATOMS * N_HID floats = 24 MB

    atom_kernel<<<N_ATOMS / 4, 256, 0, stream>>>(af, W_cf, W_fc, b_cf, b_df, ah, out);
    edge_kernel<<<EBLOCKS, 256, 0, stream>>>(dist, mi, mj, W_df, W_fc, b_df, ah, out);
}

// Round 14
// 303.106 us; speedup vs baseline: 1.4992x; 1.0097x over previous
//
#include <hip/hip_runtime.h>
#include <hip/hip_bf16.h>

#define N_ATOMS 100000
#define N_PAIRS 2000000
#define N_EMB 30
#define N_DIST 100
#define N_HID 60

#define TE 64                       // edges per tile
#define NTILES (N_PAIRS / TE)       // 31250 exact
#define EBLOCKS 768                 // 3 blocks/CU resident

typedef short bf16x8 __attribute__((ext_vector_type(8)));
typedef float f32x4 __attribute__((ext_vector_type(4)));

__device__ __forceinline__ ushort f2bf(float f) {   // cold path only
    __hip_bfloat16 h = __float2bfloat16(f);
    return __builtin_bit_cast(ushort, h);
}
__device__ __forceinline__ float bf2f(ushort u) {
    __hip_bfloat16 h = __builtin_bit_cast(__hip_bfloat16, u);
    return __bfloat162float(h);
}
// native packed f32->bf16 (RNE), 1 VALU op for 2 values
__device__ __forceinline__ unsigned cvt_pk_bf16(float lo, float hi) {
    unsigned r;
    asm("v_cvt_pk_bf16_f32 %0, %1, %2" : "=v"(r) : "v"(lo), "v"(hi));
    return r;
}
__device__ __forceinline__ ushort f2bf_rne(float x) {
    return (ushort)cvt_pk_bf16(x, x);
}
__device__ __forceinline__ float fast_tanh(float x) {
    float e = __expf(2.0f * x);
    return 1.0f - 2.0f / (e + 1.0f);
}

// ---------------- Kernel A: per-atom hidden + output init ----------------
__global__ __launch_bounds__(256) void atom_kernel(
    const float* __restrict__ af, const float* __restrict__ W_cf,
    const float* __restrict__ W_fc, const float* __restrict__ b_cf,
    const float* __restrict__ b_df, float* __restrict__ ah_out,
    float* __restrict__ out)
{
    __shared__ __align__(16) float ah_lds[4][N_HID];
    const int wave = threadIdx.x >> 6;
    const int lane = threadIdx.x & 63;
    const int n = blockIdx.x * 4 + wave;

    float ahv = 0.f;
    if (lane < N_HID) {
        ahv = b_cf[lane];
        #pragma unroll
        for (int k = 0; k < N_EMB; ++k)
            ahv = fmaf(af[(size_t)n * N_EMB + k], W_cf[k * N_HID + lane], ahv);
        ah_out[(size_t)n * N_HID + lane] = ahv;
        ah_lds[wave][lane] = ahv * b_df[lane];
    }
    __syncthreads();
    if (lane < N_EMB) {
        float s = 0.f;
        #pragma unroll
        for (int h = 0; h < N_HID; ++h)
            s = fmaf(ah_lds[wave][h], W_fc[h * N_EMB + lane], s);
        out[(size_t)n * N_EMB + lane] =
            af[(size_t)n * N_EMB + lane] - fast_tanh(s);
    }
}

// ---------------- Kernel B: r8 skeleton + VALU diet (packed cvt, hoisted idx) ----------------
__global__ __launch_bounds__(256, 3) void edge_kernel(
    const float* __restrict__ dist,
    const int* __restrict__ mi, const int* __restrict__ mj,
    const float* __restrict__ W_df, const float* __restrict__ W_fc,
    const float* __restrict__ b_df, const float* __restrict__ ah,
    float* out)
{
    __shared__ ushort A_lds[2][TE * 136];     // 34816 B (dbuf dist tile, bf16)
    __shared__ ushort T_lds[TE * 72];         // 9216 B
    __shared__ ushort S_lds[32 * 72];         // 4608 B  (S^T: [f][edge])
    __shared__ int    mis[2][TE], mjs[2][TE]; // 1024 B
    __shared__ int    seg_lds[TE];            // 256 B
    __shared__ int    seg_atom[TE];           // 256 B
    // 50176 B -> 3 blocks/CU

    const int tid = threadIdx.x;
    const int wv = tid >> 6, lane = tid & 63;
    const int l4 = lane >> 4, ln = lane & 15;
    const int h1 = wv * 16 + ln;              // stage-1 hid col for this lane

    // ---- one-time weight fragments (single bf16; r13-validated) ----
    bf16x8 wdf[4];                            // [ks]: k = ks*32 + l4*8 + i, n = h1
    #pragma unroll
    for (int ks = 0; ks < 4; ++ks) {
        #pragma unroll
        for (int i = 0; i < 8; ++i) {
            int k = ks * 32 + l4 * 8 + i;
            float f = (k < N_DIST && h1 < N_HID) ? W_df[k * N_HID + h1] : 0.f;
            wdf[ks][i] = (short)f2bf(f);
        }
    }
    bf16x8 wfc[2][2];                         // [nf][ks]
    #pragma unroll
    for (int nf = 0; nf < 2; ++nf) {
        #pragma unroll
        for (int ks = 0; ks < 2; ++ks) {
            #pragma unroll
            for (int i = 0; i < 8; ++i) {
                int k = ks * 32 + l4 * 8 + i;
                int n = nf * 16 + ln;
                float f = (k < N_HID && n < N_EMB) ? W_fc[k * N_EMB + n] : 0.f;
                wfc[nf][ks][i] = (short)f2bf(f);
            }
        }
    }
    const float bdf1 = (h1 < N_HID) ? b_df[h1] : 0.f;

    // hoisted staging indices: idx = k*256+tid -> ushort offset in A tile
    int sdst[7];
    #pragma unroll
    for (int k = 0; k < 7; ++k) {
        int idx = k * 256 + tid;
        sdst[k] = (idx / 25) * 136 + (idx % 25) * 4;
    }

    // zero A pad columns [100..136) in both buffers (never rewritten)
    for (int idx = tid; idx < 2 * TE * 36; idx += 256) {
        int b = idx / (TE * 36), rem = idx % (TE * 36);
        int r = rem / 36, c = 100 + rem % 36;
        A_lds[b][r * 136 + c] = 0;
    }

    const int t0 = (int)(((long long)blockIdx.x * NTILES) / EBLOCKS);
    const int t1 = (int)(((long long)(blockIdx.x + 1) * NTILES) / EBLOCKS);

    f32x4 pf[7];
    int pmi = 0, pmj = 0;

    auto stage_issue = [&](int t) {
        const f32x4* src = (const f32x4*)(dist + (size_t)t * TE * N_DIST);
        #pragma unroll
        for (int k = 0; k < 6; ++k)
            pf[k] = __builtin_nontemporal_load(&src[k * 256 + tid]);
        if (tid < 64) {
            pf[6] = __builtin_nontemporal_load(&src[6 * 256 + tid]);
            pmi = mi[t * TE + tid];
            pmj = mj[t * TE + tid];
        }
    };
    auto stage_write = [&](int buf) {
        #pragma unroll
        for (int k = 0; k < 7; ++k) {
            if (k < 6 || tid < 64) {
                f32x4 v = pf[k];
                uint2 w;
                w.x = cvt_pk_bf16(v[0], v[1]);
                w.y = cvt_pk_bf16(v[2], v[3]);
                *(uint2*)&A_lds[buf][sdst[k]] = w;
            }
        }
        if (tid < 64) { mis[buf][tid] = pmi; mjs[buf][tid] = pmj; }
    };

    // prologue: stage tile t0 into buffer 0
    stage_issue(t0);
    stage_write(0);
    __syncthreads();

    int cur = 0;
    for (int t = t0; t < t1; ++t) {
        const bool hasnext = (t + 1 < t1);

        // ---- gather first (its waitcnt leaves the dist prefetch in flight) ----
        float ahg[4][4];
        #pragma unroll
        for (int m = 0; m < 4; ++m) {
            #pragma unroll
            for (int r = 0; r < 4; ++r) {
                int el = 16 * m + l4 * 4 + r;
                int j = mjs[cur][el];
                ahg[m][r] = (h1 < N_HID) ? ah[(size_t)j * N_HID + h1] : 0.f;
            }
        }

        if (hasnext) stage_issue(t + 1);

        // ---- stage-1 MFMA: 64 edges x 16 hids ----
        f32x4 acc1[4] = {{0,0,0,0},{0,0,0,0},{0,0,0,0},{0,0,0,0}};
        #pragma unroll
        for (int ks = 0; ks < 4; ++ks) {
            #pragma unroll
            for (int m = 0; m < 4; ++m) {
                bf16x8 a = *(const bf16x8*)&A_lds[cur][(16 * m + ln) * 136 + ks * 32 + l4 * 8];
                acc1[m] = __builtin_amdgcn_mfma_f32_16x16x32_bf16(a, wdf[ks], acc1[m], 0, 0, 0);
            }
        }

        // ---- t = (dh + b_df) * ah -> bf16 -> T_lds ----
        // (h1>=60: wdf,bdf1,ahg all zero-padded -> tv==0 exactly; no guard needed)
        #pragma unroll
        for (int m = 0; m < 4; ++m) {
            #pragma unroll
            for (int r = 0; r < 4; ++r) {
                int row = 16 * m + l4 * 4 + r;
                float tv = (acc1[m][r] + bdf1) * ahg[m][r];
                T_lds[row * 72 + h1] = f2bf_rne(tv);
            }
        }
        __syncthreads();   // B2: T ready

        // ---- stage-2 MFMA: 16 edges x 32 f ----
        f32x4 acc2[2] = {{0,0,0,0},{0,0,0,0}};
        #pragma unroll
        for (int ks = 0; ks < 2; ++ks) {
            bf16x8 a2 = *(const bf16x8*)&T_lds[(16 * wv + ln) * 72 + ks * 32 + l4 * 8];
            #pragma unroll
            for (int nf = 0; nf < 2; ++nf)
                acc2[nf] = __builtin_amdgcn_mfma_f32_16x16x32_bf16(a2, wfc[nf][ks], acc2[nf], 0, 0, 0);
        }
        // tanh -> S^T (bf16), packed pairs + b64 writes; rows f>=30 exact zeros
        #pragma unroll
        for (int nf = 0; nf < 2; ++nf) {
            uint2 w;
            w.x = cvt_pk_bf16(fast_tanh(acc2[nf][0]), fast_tanh(acc2[nf][1]));
            w.y = cvt_pk_bf16(fast_tanh(acc2[nf][2]), fast_tanh(acc2[nf][3]));
            *(uint2*)&S_lds[(nf * 16 + ln) * 72 + 16 * wv + l4 * 4] = w;
        }

        // write next tile's A while S settles
        if (hasnext) stage_write(cur ^ 1);

        __syncthreads();   // B3: S ready, next A ready

        // ---- per-tile segment metadata (redundant per wave, identical) ----
        int m_e = mis[cur][lane];
        int prevv = __shfl_up(m_e, 1);
        bool changed = (lane > 0) && (m_e != prevv);
        unsigned long long bmask = __ballot(changed);
        int segl = __popcll(bmask & ((2ull << lane) - 1ull));
        if (lane == 0 || changed) seg_atom[segl] = m_e;
        seg_lds[lane] = segl;
        int nseg = __popcll(bmask) + 1;

        // ---- selector MFMA: C[seg][f] = sel[seg][e] @ S[e][f] ----
        int myseg = 16 * wv + ln;
        f32x4 acc3[2] = {{0,0,0,0},{0,0,0,0}};
        #pragma unroll
        for (int ks = 0; ks < 2; ++ks) {
            bf16x8 sfr;
            const int* sp = &seg_lds[ks * 32 + l4 * 8];
            #pragma unroll
            for (int i = 0; i < 8; ++i)
                sfr[i] = (sp[i] == myseg) ? (short)0x3F80 : (short)0;
            #pragma unroll
            for (int nf = 0; nf < 2; ++nf) {
                bf16x8 b = *(const bf16x8*)&S_lds[(nf * 16 + ln) * 72 + ks * 32 + l4 * 8];
                acc3[nf] = __builtin_amdgcn_mfma_f32_16x16x32_bf16(sfr, b, acc3[nf], 0, 0, 0);
            }
        }
        // ---- flush: one atomicAdd per (present segment, f), conflict-free ----
        #pragma unroll
        for (int nf = 0; nf < 2; ++nf) {
            #pragma unroll
            for (int r = 0; r < 4; ++r) {
                int gs = 16 * wv + l4 * 4 + r;
                int f = nf * 16 + ln;
                if (gs < nseg && f < N_EMB) {
                    int atomId = seg_atom[gs];
                    atomicAdd(&out[(size_t)atomId * N_EMB + f], acc3[nf][r]);
                }
            }
        }
        cur ^= 1;
    }
}

extern "C" void kernel_launch(void* const* d_in, const int* in_sizes, int n_in,
                              void* d_out, int out_size, void* d_ws, size_t ws_size,
                              hipStream_t stream) {
    const float* af   = (const float*)d_in[0];
    const float* dist = (const float*)d_in[1];
    const int*   mi   = (const int*)d_in[2];
    const int*   mj   = (const int*)d_in[3];
    const float* W_cf = (const float*)d_in[4];
    const float* W_df = (const float*)d_in[5];
    const float* W_fc = (const float*)d_in[6];
    const float* b_cf = (const float*)d_in[7];
    const float* b_df = (const float*)d_in[8];
    float* out = (float*)d_out;
    float* ah  = (float*)d_ws;   // N_ATOMS * N_HID floats = 24 MB

    atom_kernel<<<N_ATOMS / 4, 256, 0, stream>>>(af, W_cf, W_fc, b_cf, b_df, ah, out);
    edge_kernel<<<EBLOCKS, 256, 0, stream>>>(dist, mi, mj, W_df, W_fc, b_df, ah, out);
}